// Round 1
// baseline (3109.839 us; speedup 1.0000x reference)
//
#include <hip/hip_runtime.h>

#define NN 100000
#define DD 128
#define EE 1600000
#define BN_EPS 1e-5f

// ---------------- degree histogram ----------------
__global__ void deg_kernel(const int* __restrict__ src, const int* __restrict__ dst,
                           int* __restrict__ outdeg, int* __restrict__ indeg, int E) {
    int i = blockIdx.x * blockDim.x + threadIdx.x;
    if (i < E) {
        atomicAdd(&outdeg[src[i]], 1);
        atomicAdd(&indeg[dst[i]], 1);
    }
}

// ---------------- norms ----------------
__global__ void norm_kernel(const int* __restrict__ outdeg, const int* __restrict__ indeg,
                            float* __restrict__ ns, float* __restrict__ nd, int n) {
    int i = blockIdx.x * blockDim.x + threadIdx.x;
    if (i < n) {
        ns[i] = rsqrtf(fmaxf((float)outdeg[i], 1.0f));
        nd[i] = rsqrtf(fmaxf((float)indeg[i], 1.0f));
    }
}

// ---------------- edge scatter: agg[dst] += feats[src] * ns[src] ----------------
// one thread = one (edge, float4-chunk); 32 threads cover an edge's 128 floats
__global__ void scatter_kernel(const float4* __restrict__ feats4,
                               const int* __restrict__ src, const int* __restrict__ dst,
                               const float* __restrict__ ns,
                               float* __restrict__ agg, int E) {
    int t = blockIdx.x * blockDim.x + threadIdx.x;
    int e = t >> 5;
    int c = t & 31;
    if (e < E) {
        int s = src[e];
        int d = dst[e];
        float w = ns[s];
        float4 v = feats4[s * 32 + c];
        float* out = agg + (size_t)d * DD + c * 4;
        atomicAdd(out + 0, v.x * w);
        atomicAdd(out + 1, v.y * w);
        atomicAdd(out + 2, v.z * w);
        atomicAdd(out + 3, v.w * w);
    }
}

// ---------------- fused dual GEMM + bias + relu + add ----------------
// y[n][j] = relu((agg[n]*nd[n]) @ W + b)[j] + relu(feats[n] @ Wr + br)[j]
// block = 256 threads, 32 rows per block, full 128 cols. 3125 blocks (exact).
__global__ __launch_bounds__(256) void gemm_kernel(
    const float* __restrict__ agg, const float* __restrict__ feats,
    const float* __restrict__ nd,
    const float* __restrict__ W, const float* __restrict__ b,
    const float* __restrict__ Wr, const float* __restrict__ br,
    float* __restrict__ y) {
    __shared__ float As[32 * 128];
    __shared__ float Fs[32 * 128];
    const int block_row = blockIdx.x * 32;
    const int tid = threadIdx.x;

    // stage 32 rows of agg (scaled by nd) and feats: 1024 float4, 4 per thread
    for (int i = tid; i < 1024; i += 256) {
        int r = i >> 5;
        int c4 = i & 31;
        int row = block_row + r;
        float4 av = ((const float4*)agg)[(size_t)row * 32 + c4];
        float s = nd[row];
        av.x *= s; av.y *= s; av.z *= s; av.w *= s;
        ((float4*)As)[i] = av;
        ((float4*)Fs)[i] = ((const float4*)feats)[(size_t)row * 32 + c4];
    }
    __syncthreads();

    const int rr = tid >> 5;  // 0..7  -> rows rr*4 .. rr*4+3
    const int cc = tid & 31;  // 0..31 -> cols cc*4 .. cc*4+3

    float accC[4][4] = {{0.f}};
    float accR[4][4] = {{0.f}};

    for (int k4 = 0; k4 < 32; ++k4) {
        float4 a4[4], f4[4];
#pragma unroll
        for (int r = 0; r < 4; ++r) {
            a4[r] = ((const float4*)As)[(rr * 4 + r) * 32 + k4];
            f4[r] = ((const float4*)Fs)[(rr * 4 + r) * 32 + k4];
        }
#pragma unroll
        for (int kk = 0; kk < 4; ++kk) {
            int k = k4 * 4 + kk;
            float4 wv = ((const float4*)W)[k * 32 + cc];
            float4 wrv = ((const float4*)Wr)[k * 32 + cc];
#pragma unroll
            for (int r = 0; r < 4; ++r) {
                float a = (kk == 0) ? a4[r].x : (kk == 1) ? a4[r].y : (kk == 2) ? a4[r].z : a4[r].w;
                float f = (kk == 0) ? f4[r].x : (kk == 1) ? f4[r].y : (kk == 2) ? f4[r].z : f4[r].w;
                accC[r][0] += a * wv.x;  accC[r][1] += a * wv.y;
                accC[r][2] += a * wv.z;  accC[r][3] += a * wv.w;
                accR[r][0] += f * wrv.x; accR[r][1] += f * wrv.y;
                accR[r][2] += f * wrv.z; accR[r][3] += f * wrv.w;
            }
        }
    }

    float4 bv = ((const float4*)b)[cc];
    float4 brv = ((const float4*)br)[cc];
#pragma unroll
    for (int r = 0; r < 4; ++r) {
        int row = block_row + rr * 4 + r;
        float4 o;
        o.x = fmaxf(accC[r][0] + bv.x, 0.f) + fmaxf(accR[r][0] + brv.x, 0.f);
        o.y = fmaxf(accC[r][1] + bv.y, 0.f) + fmaxf(accR[r][1] + brv.y, 0.f);
        o.z = fmaxf(accC[r][2] + bv.z, 0.f) + fmaxf(accR[r][2] + brv.z, 0.f);
        o.w = fmaxf(accC[r][3] + bv.w, 0.f) + fmaxf(accR[r][3] + brv.w, 0.f);
        ((float4*)y)[(size_t)row * 32 + cc] = o;
    }
}

// ---------------- BN column sums ----------------
__global__ void colsum_kernel(const float* __restrict__ y,
                              float* __restrict__ colsum, float* __restrict__ colsumsq) {
    __shared__ float s_sum[256];
    __shared__ float s_sq[256];
    int col = threadIdx.x & 127;
    int half = threadIdx.x >> 7;
    float sum = 0.f, sq = 0.f;
    for (int row = blockIdx.x * 2 + half; row < NN; row += gridDim.x * 2) {
        float v = y[(size_t)row * DD + col];
        sum += v;
        sq += v * v;
    }
    s_sum[threadIdx.x] = sum;
    s_sq[threadIdx.x] = sq;
    __syncthreads();
    if (threadIdx.x < 128) {
        sum = s_sum[threadIdx.x] + s_sum[threadIdx.x + 128];
        sq = s_sq[threadIdx.x] + s_sq[threadIdx.x + 128];
        atomicAdd(&colsum[col], sum);
        atomicAdd(&colsumsq[col], sq);
    }
}

// ---------------- BN stats finalize ----------------
__global__ void stats_kernel(const float* __restrict__ colsum, const float* __restrict__ colsumsq,
                             const float* __restrict__ gamma, const float* __restrict__ beta,
                             float* __restrict__ scale, float* __restrict__ shift) {
    int j = threadIdx.x;
    if (j < DD) {
        float inv_n = 1.0f / (float)NN;
        float mean = colsum[j] * inv_n;
        float var = colsumsq[j] * inv_n - mean * mean;
        float sc = gamma[j] * rsqrtf(var + BN_EPS);
        scale[j] = sc;
        shift[j] = beta[j] - mean * sc;
    }
}

// ---------------- BN apply (in place on d_out) ----------------
__global__ void apply_kernel(float4* __restrict__ y4,
                             const float* __restrict__ scale, const float* __restrict__ shift,
                             int total4) {
    int i = blockIdx.x * blockDim.x + threadIdx.x;
    if (i < total4) {
        int c4 = i & 31;
        float4 v = y4[i];
        float4 sc = ((const float4*)scale)[c4];
        float4 sh = ((const float4*)shift)[c4];
        v.x = v.x * sc.x + sh.x;
        v.y = v.y * sc.y + sh.y;
        v.z = v.z * sc.z + sh.z;
        v.w = v.w * sc.w + sh.w;
        y4[i] = v;
    }
}

extern "C" void kernel_launch(void* const* d_in, const int* in_sizes, int n_in,
                              void* d_out, int out_size, void* d_ws, size_t ws_size,
                              hipStream_t stream) {
    const float* feats = (const float*)d_in[0];
    const int* src = (const int*)d_in[1];
    const int* dst = (const int*)d_in[2];
    const float* W = (const float*)d_in[3];
    const float* b = (const float*)d_in[4];
    const float* Wr = (const float*)d_in[5];
    const float* br = (const float*)d_in[6];
    const float* gamma = (const float*)d_in[7];
    const float* beta = (const float*)d_in[8];
    float* y = (float*)d_out;

    // workspace carve
    char* ws = (char*)d_ws;
    float* agg = (float*)ws;                                   // NN*DD floats = 51.2 MB
    int* outdeg = (int*)(ws + (size_t)NN * DD * sizeof(float)); // NN ints
    int* indeg = outdeg + NN;                                   // NN ints
    float* ns = (float*)(indeg + NN);                           // NN floats
    float* nd = ns + NN;                                        // NN floats
    float* colsum = nd + NN;                                    // 128
    float* colsumsq = colsum + DD;                              // 128
    float* scale = colsumsq + DD;                               // 128
    float* shift = scale + DD;                                  // 128

    // zero-init (ws is poisoned 0xAA before every call)
    hipMemsetAsync(agg, 0, (size_t)NN * DD * sizeof(float), stream);
    hipMemsetAsync(outdeg, 0, 2 * (size_t)NN * sizeof(int), stream);
    hipMemsetAsync(colsum, 0, 2 * (size_t)DD * sizeof(float), stream);

    // degrees
    deg_kernel<<<(EE + 255) / 256, 256, 0, stream>>>(src, dst, outdeg, indeg, EE);
    // norms
    norm_kernel<<<(NN + 255) / 256, 256, 0, stream>>>(outdeg, indeg, ns, nd, NN);
    // scatter-aggregate
    {
        long long total = (long long)EE * 32;
        int blocks = (int)((total + 255) / 256);
        scatter_kernel<<<blocks, 256, 0, stream>>>((const float4*)feats, src, dst, ns, agg, EE);
    }
    // fused dual GEMM -> y (pre-BN)
    gemm_kernel<<<NN / 32, 256, 0, stream>>>(agg, feats, nd, W, b, Wr, br, y);
    // BN stats
    colsum_kernel<<<256, 256, 0, stream>>>(y, colsum, colsumsq);
    stats_kernel<<<1, 128, 0, stream>>>(colsum, colsumsq, gamma, beta, scale, shift);
    // BN apply
    {
        int total4 = NN * DD / 4;
        apply_kernel<<<(total4 + 255) / 256, 256, 0, stream>>>((float4*)y, scale, shift, total4);
    }
}

// Round 2
// 871.686 us; speedup vs baseline: 3.5676x; 3.5676x over previous
//
#include <hip/hip_runtime.h>

#define NN 100000
#define DD 128
#define EE 1600000
#define BN_EPS 1e-5f

// ---------------- degree histogram ----------------
__global__ void deg_kernel(const int* __restrict__ src, const int* __restrict__ dst,
                           int* __restrict__ outdeg, int* __restrict__ indeg, int E) {
    int i = blockIdx.x * blockDim.x + threadIdx.x;
    if (i < E) {
        atomicAdd(&outdeg[src[i]], 1);
        atomicAdd(&indeg[dst[i]], 1);
    }
}

// ---------------- norms ----------------
__global__ void norm_kernel(const int* __restrict__ outdeg, const int* __restrict__ indeg,
                            float* __restrict__ ns, float* __restrict__ nd, int n) {
    int i = blockIdx.x * blockDim.x + threadIdx.x;
    if (i < n) {
        ns[i] = rsqrtf(fmaxf((float)outdeg[i], 1.0f));
        nd[i] = rsqrtf(fmaxf((float)indeg[i], 1.0f));
    }
}

// ---------------- exclusive scan of indeg -> row_ofs (N+1) and cursor copy ----------------
// single block, 1024 threads, each handles a contiguous chunk
__global__ __launch_bounds__(1024) void scan_kernel(const int* __restrict__ indeg,
                                                    int* __restrict__ row_ofs,
                                                    int* __restrict__ cursor) {
    __shared__ int s[1024];
    const int T = 1024;
    int tid = threadIdx.x;
    int chunk = (NN + T - 1) / T;  // 98
    int begin = tid * chunk;
    int end = begin + chunk; if (end > NN) end = NN;
    int sum = 0;
    for (int i = begin; i < end; ++i) sum += indeg[i];
    s[tid] = sum;
    __syncthreads();
    // inclusive Hillis-Steele scan in LDS
    for (int off = 1; off < T; off <<= 1) {
        int t = (tid >= off) ? s[tid - off] : 0;
        __syncthreads();
        s[tid] += t;
        __syncthreads();
    }
    int run = s[tid] - sum;  // exclusive prefix for this chunk
    for (int i = begin; i < end; ++i) {
        row_ofs[i] = run;
        cursor[i] = run;
        run += indeg[i];
    }
    if (tid == T - 1) row_ofs[NN] = run;
}

// ---------------- CSR fill: bucket srcs by dst ----------------
__global__ void fill_kernel(const int* __restrict__ src, const int* __restrict__ dst,
                            int* __restrict__ cursor, int* __restrict__ e_src, int E) {
    int i = blockIdx.x * blockDim.x + threadIdx.x;
    if (i < E) {
        int d = dst[i];
        int pos = atomicAdd(&cursor[d], 1);
        e_src[pos] = src[i];
    }
}

// ---------------- fused gather + dual GEMM + bias/relu/add + BN colsum ----------------
// block = 256 threads, 32 nodes/block, 3125 blocks (exact)
__global__ __launch_bounds__(256) void gg_kernel(
    const float* __restrict__ feats, const float* __restrict__ ns, const float* __restrict__ nd,
    const int* __restrict__ row_ofs, const int* __restrict__ e_src,
    const float* __restrict__ W, const float* __restrict__ b,
    const float* __restrict__ Wr, const float* __restrict__ br,
    float* __restrict__ y, float* __restrict__ colsum, float* __restrict__ colsumsq) {
    __shared__ float As[32 * 128];
    __shared__ float Fs[32 * 128];
    const int block_row = blockIdx.x * 32;
    const int tid = threadIdx.x;
    const int lane = tid & 31;
    const int grp = tid >> 5;  // 0..7
    const float4* feats4 = (const float4*)feats;

    // stage feats rows
    for (int i = tid; i < 1024; i += 256) {
        int r = i >> 5;
        int c4 = i & 31;
        ((float4*)Fs)[i] = feats4[(size_t)(block_row + r) * 32 + c4];
    }

    // gather-aggregate: each 32-lane group handles 4 nodes
    for (int n = 0; n < 4; ++n) {
        int nl = grp * 4 + n;            // local node 0..31
        int node = block_row + nl;
        int beg = row_ofs[node];
        int end = row_ofs[node + 1];
        float4 acc = {0.f, 0.f, 0.f, 0.f};
        int e = beg;
        for (; e + 1 < end; e += 2) {
            int s0 = e_src[e], s1 = e_src[e + 1];
            float w0 = ns[s0], w1 = ns[s1];
            float4 v0 = feats4[s0 * 32 + lane];
            float4 v1 = feats4[s1 * 32 + lane];
            acc.x += v0.x * w0 + v1.x * w1;
            acc.y += v0.y * w0 + v1.y * w1;
            acc.z += v0.z * w0 + v1.z * w1;
            acc.w += v0.w * w0 + v1.w * w1;
        }
        if (e < end) {
            int s0 = e_src[e];
            float w0 = ns[s0];
            float4 v0 = feats4[s0 * 32 + lane];
            acc.x += v0.x * w0; acc.y += v0.y * w0;
            acc.z += v0.z * w0; acc.w += v0.w * w0;
        }
        float snd = nd[node];
        acc.x *= snd; acc.y *= snd; acc.z *= snd; acc.w *= snd;
        ((float4*)As)[nl * 32 + lane] = acc;
    }
    __syncthreads();

    const int rr = tid >> 5;  // rows rr*4 .. rr*4+3
    const int cc = tid & 31;  // cols cc*4 .. cc*4+3

    float accC[4][4] = {{0.f}};
    float accR[4][4] = {{0.f}};

    for (int k4 = 0; k4 < 32; ++k4) {
        float4 a4[4], f4[4];
#pragma unroll
        for (int r = 0; r < 4; ++r) {
            a4[r] = ((const float4*)As)[(rr * 4 + r) * 32 + k4];
            f4[r] = ((const float4*)Fs)[(rr * 4 + r) * 32 + k4];
        }
#pragma unroll
        for (int kk = 0; kk < 4; ++kk) {
            int k = k4 * 4 + kk;
            float4 wv = ((const float4*)W)[k * 32 + cc];
            float4 wrv = ((const float4*)Wr)[k * 32 + cc];
#pragma unroll
            for (int r = 0; r < 4; ++r) {
                float a = (kk == 0) ? a4[r].x : (kk == 1) ? a4[r].y : (kk == 2) ? a4[r].z : a4[r].w;
                float f = (kk == 0) ? f4[r].x : (kk == 1) ? f4[r].y : (kk == 2) ? f4[r].z : f4[r].w;
                accC[r][0] += a * wv.x;  accC[r][1] += a * wv.y;
                accC[r][2] += a * wv.z;  accC[r][3] += a * wv.w;
                accR[r][0] += f * wrv.x; accR[r][1] += f * wrv.y;
                accR[r][2] += f * wrv.z; accR[r][3] += f * wrv.w;
            }
        }
    }

    float4 bv = ((const float4*)b)[cc];
    float4 brv = ((const float4*)br)[cc];
    float csum[4] = {0.f, 0.f, 0.f, 0.f};
    float csq[4] = {0.f, 0.f, 0.f, 0.f};
#pragma unroll
    for (int r = 0; r < 4; ++r) {
        int row = block_row + rr * 4 + r;
        float4 o;
        o.x = fmaxf(accC[r][0] + bv.x, 0.f) + fmaxf(accR[r][0] + brv.x, 0.f);
        o.y = fmaxf(accC[r][1] + bv.y, 0.f) + fmaxf(accR[r][1] + brv.y, 0.f);
        o.z = fmaxf(accC[r][2] + bv.z, 0.f) + fmaxf(accR[r][2] + brv.z, 0.f);
        o.w = fmaxf(accC[r][3] + bv.w, 0.f) + fmaxf(accR[r][3] + brv.w, 0.f);
        ((float4*)y)[(size_t)row * 32 + cc] = o;
        csum[0] += o.x; csum[1] += o.y; csum[2] += o.z; csum[3] += o.w;
        csq[0] += o.x * o.x; csq[1] += o.y * o.y; csq[2] += o.z * o.z; csq[3] += o.w * o.w;
    }

    // block-level column reduction: reuse As (sum) and Fs (sumsq)
    __syncthreads();
#pragma unroll
    for (int j = 0; j < 4; ++j) {
        As[rr * 128 + cc * 4 + j] = csum[j];
        Fs[rr * 128 + cc * 4 + j] = csq[j];
    }
    __syncthreads();
    if (tid < 128) {
        float s = 0.f, q = 0.f;
#pragma unroll
        for (int g = 0; g < 8; ++g) {
            s += As[g * 128 + tid];
            q += Fs[g * 128 + tid];
        }
        atomicAdd(&colsum[tid], s);
        atomicAdd(&colsumsq[tid], q);
    }
}

// ---------------- BN stats finalize ----------------
__global__ void stats_kernel(const float* __restrict__ colsum, const float* __restrict__ colsumsq,
                             const float* __restrict__ gamma, const float* __restrict__ beta,
                             float* __restrict__ scale, float* __restrict__ shift) {
    int j = threadIdx.x;
    if (j < DD) {
        float inv_n = 1.0f / (float)NN;
        float mean = colsum[j] * inv_n;
        float var = colsumsq[j] * inv_n - mean * mean;
        float sc = gamma[j] * rsqrtf(var + BN_EPS);
        scale[j] = sc;
        shift[j] = beta[j] - mean * sc;
    }
}

// ---------------- BN apply (in place on d_out) ----------------
__global__ void apply_kernel(float4* __restrict__ y4,
                             const float* __restrict__ scale, const float* __restrict__ shift,
                             int total4) {
    int i = blockIdx.x * blockDim.x + threadIdx.x;
    if (i < total4) {
        int c4 = i & 31;
        float4 v = y4[i];
        float4 sc = ((const float4*)scale)[c4];
        float4 sh = ((const float4*)shift)[c4];
        v.x = v.x * sc.x + sh.x;
        v.y = v.y * sc.y + sh.y;
        v.z = v.z * sc.z + sh.z;
        v.w = v.w * sc.w + sh.w;
        y4[i] = v;
    }
}

extern "C" void kernel_launch(void* const* d_in, const int* in_sizes, int n_in,
                              void* d_out, int out_size, void* d_ws, size_t ws_size,
                              hipStream_t stream) {
    const float* feats = (const float*)d_in[0];
    const int* src = (const int*)d_in[1];
    const int* dst = (const int*)d_in[2];
    const float* W = (const float*)d_in[3];
    const float* b = (const float*)d_in[4];
    const float* Wr = (const float*)d_in[5];
    const float* br = (const float*)d_in[6];
    const float* gamma = (const float*)d_in[7];
    const float* beta = (const float*)d_in[8];
    float* y = (float*)d_out;

    // workspace carve (all int/float = 4B)
    char* ws = (char*)d_ws;
    int* outdeg = (int*)ws;               // NN
    int* indeg = outdeg + NN;             // NN
    float* ns = (float*)(indeg + NN);     // NN
    float* nd = ns + NN;                  // NN
    int* row_ofs = (int*)(nd + NN);       // NN+1
    int* cursor = row_ofs + NN + 1;       // NN
    int* e_src = cursor + NN;             // EE
    float* colsum = (float*)(e_src + EE); // 128
    float* colsumsq = colsum + DD;        // 128
    float* scale = colsumsq + DD;         // 128
    float* shift = scale + DD;            // 128

    // zero-init what needs zeros (ws poisoned 0xAA before every call)
    hipMemsetAsync(outdeg, 0, 2 * (size_t)NN * sizeof(int), stream);
    hipMemsetAsync(colsum, 0, 2 * (size_t)DD * sizeof(float), stream);

    deg_kernel<<<(EE + 255) / 256, 256, 0, stream>>>(src, dst, outdeg, indeg, EE);
    norm_kernel<<<(NN + 255) / 256, 256, 0, stream>>>(outdeg, indeg, ns, nd, NN);
    scan_kernel<<<1, 1024, 0, stream>>>(indeg, row_ofs, cursor);
    fill_kernel<<<(EE + 255) / 256, 256, 0, stream>>>(src, dst, cursor, e_src, EE);
    gg_kernel<<<NN / 32, 256, 0, stream>>>(feats, ns, nd, row_ofs, e_src,
                                           W, b, Wr, br, y, colsum, colsumsq);
    stats_kernel<<<1, 128, 0, stream>>>(colsum, colsumsq, gamma, beta, scale, shift);
    {
        int total4 = NN * DD / 4;
        apply_kernel<<<(total4 + 255) / 256, 256, 0, stream>>>((float4*)y, scale, shift, total4);
    }
}

// Round 3
// 618.122 us; speedup vs baseline: 5.0311x; 1.4102x over previous
//
#include <hip/hip_runtime.h>

#define NN 100000
#define DD 128
#define EE 1600000
#define BN_EPS 1e-5f

__device__ __forceinline__ unsigned short bf16r(float f) {
    unsigned u = __float_as_uint(f);
    u += 0x7FFF + ((u >> 16) & 1);   // round-to-nearest-even
    return (unsigned short)(u >> 16);
}
__device__ __forceinline__ float bf2f(unsigned short h) {
    return __uint_as_float((unsigned)h << 16);
}

// ---------------- degree histogram (int4 edge loads) ----------------
__global__ void deg4_kernel(const int4* __restrict__ src4, const int4* __restrict__ dst4,
                            int* __restrict__ outdeg, int* __restrict__ indeg) {
    int i = blockIdx.x * blockDim.x + threadIdx.x;
    if (i < EE / 4) {
        int4 s = src4[i];
        int4 d = dst4[i];
        atomicAdd(&outdeg[s.x], 1); atomicAdd(&outdeg[s.y], 1);
        atomicAdd(&outdeg[s.z], 1); atomicAdd(&outdeg[s.w], 1);
        atomicAdd(&indeg[d.x], 1); atomicAdd(&indeg[d.y], 1);
        atomicAdd(&indeg[d.z], 1); atomicAdd(&indeg[d.w], 1);
    }
}

// ---------------- scan phase 1: per-block inclusive scan of indeg ----------------
__global__ __launch_bounds__(1024) void scan1_kernel(const int* __restrict__ indeg,
                                                     int* __restrict__ partial,
                                                     int* __restrict__ blocksum) {
    __shared__ int s[1024];
    int t = threadIdx.x;
    int idx = blockIdx.x * 1024 + t;
    int v = (idx < NN) ? indeg[idx] : 0;
    s[t] = v;
    __syncthreads();
    for (int off = 1; off < 1024; off <<= 1) {
        int x = (t >= off) ? s[t - off] : 0;
        __syncthreads();
        s[t] += x;
        __syncthreads();
    }
    if (idx < NN) partial[idx] = s[t] - v;  // exclusive within block
    if (t == 1023) blocksum[blockIdx.x] = s[t];
}

// ---------------- scan phase 2: scan the 98 block sums ----------------
__global__ void scan2_kernel(const int* __restrict__ blocksum, int* __restrict__ blockofs) {
    __shared__ int s[128];
    int t = threadIdx.x;
    int v = (t < 98) ? blocksum[t] : 0;
    s[t] = v;
    __syncthreads();
    for (int off = 1; off < 128; off <<= 1) {
        int x = (t >= off) ? s[t - off] : 0;
        __syncthreads();
        s[t] += x;
        __syncthreads();
    }
    if (t < 98) blockofs[t] = s[t] - v;
}

// ---------------- scan phase 3 + norms: finalize row_ofs/cursor, compute ns/nd ----------------
__global__ void scan3_kernel(const int* __restrict__ partial, const int* __restrict__ blockofs,
                             const int* __restrict__ outdeg, const int* __restrict__ indeg,
                             int* __restrict__ row_ofs, int* __restrict__ cursor,
                             float* __restrict__ ns, float* __restrict__ nd) {
    int i = blockIdx.x * blockDim.x + threadIdx.x;
    if (i < NN) {
        int ro = partial[i] + blockofs[i >> 10];
        row_ofs[i] = ro;
        cursor[i] = ro;
        ns[i] = rsqrtf(fmaxf((float)outdeg[i], 1.0f));
        nd[i] = rsqrtf(fmaxf((float)indeg[i], 1.0f));
        if (i == 0) row_ofs[NN] = EE;
    }
}

// ---------------- feats -> bf16 pre-scaled by ns ----------------
__global__ void cvt_kernel(const float4* __restrict__ feats4, const float* __restrict__ ns,
                           ushort4* __restrict__ fb4) {
    int i = blockIdx.x * blockDim.x + threadIdx.x;  // NN*32 = 3.2M
    if (i < NN * 32) {
        float s = ns[i >> 5];
        float4 v = feats4[i];
        ushort4 h;
        h.x = bf16r(v.x * s);
        h.y = bf16r(v.y * s);
        h.z = bf16r(v.z * s);
        h.w = bf16r(v.w * s);
        fb4[i] = h;
    }
}

// ---------------- CSR fill (int4 edge loads) ----------------
__global__ void fill4_kernel(const int4* __restrict__ src4, const int4* __restrict__ dst4,
                             int* __restrict__ cursor, int* __restrict__ e_src) {
    int i = blockIdx.x * blockDim.x + threadIdx.x;
    if (i < EE / 4) {
        int4 s = src4[i];
        int4 d = dst4[i];
        e_src[atomicAdd(&cursor[d.x], 1)] = s.x;
        e_src[atomicAdd(&cursor[d.y], 1)] = s.y;
        e_src[atomicAdd(&cursor[d.z], 1)] = s.z;
        e_src[atomicAdd(&cursor[d.w], 1)] = s.w;
    }
}

// ---------------- fused gather + dual GEMM + bias/relu/add + BN colsum ----------------
// block = 256 threads, 32 nodes/block, 3125 blocks (exact)
__global__ __launch_bounds__(256) void gg_kernel(
    const float* __restrict__ feats, const ushort4* __restrict__ fb4,
    const float* __restrict__ nd,
    const int* __restrict__ row_ofs, const int* __restrict__ e_src,
    const float* __restrict__ W, const float* __restrict__ b,
    const float* __restrict__ Wr, const float* __restrict__ br,
    float* __restrict__ y, float* __restrict__ colsum, float* __restrict__ colsumsq) {
    __shared__ float As[32 * 128];
    __shared__ float Fs[32 * 128];
    const int block_row = blockIdx.x * 32;
    const int tid = threadIdx.x;
    const int lane = tid & 31;
    const int grp = tid >> 5;  // 0..7
    const float4* feats4 = (const float4*)feats;

    // stage fp32 feats rows for the residual GEMM
    for (int i = tid; i < 1024; i += 256) {
        int r = i >> 5;
        int c4 = i & 31;
        ((float4*)Fs)[i] = feats4[(size_t)(block_row + r) * 32 + c4];
    }

    // gather-aggregate from bf16 pre-scaled table: each 32-lane group does 4 nodes
    for (int n = 0; n < 4; ++n) {
        int nl = grp * 4 + n;
        int node = block_row + nl;
        int beg = row_ofs[node];
        int end = row_ofs[node + 1];
        float4 acc0 = {0.f, 0.f, 0.f, 0.f};
        float4 acc1 = {0.f, 0.f, 0.f, 0.f};
        int e = beg;
        for (; e + 3 < end; e += 4) {
            int s0 = e_src[e], s1 = e_src[e + 1], s2 = e_src[e + 2], s3 = e_src[e + 3];
            ushort4 u0 = fb4[s0 * 32 + lane];
            ushort4 u1 = fb4[s1 * 32 + lane];
            ushort4 u2 = fb4[s2 * 32 + lane];
            ushort4 u3 = fb4[s3 * 32 + lane];
            acc0.x += bf2f(u0.x); acc0.y += bf2f(u0.y); acc0.z += bf2f(u0.z); acc0.w += bf2f(u0.w);
            acc1.x += bf2f(u1.x); acc1.y += bf2f(u1.y); acc1.z += bf2f(u1.z); acc1.w += bf2f(u1.w);
            acc0.x += bf2f(u2.x); acc0.y += bf2f(u2.y); acc0.z += bf2f(u2.z); acc0.w += bf2f(u2.w);
            acc1.x += bf2f(u3.x); acc1.y += bf2f(u3.y); acc1.z += bf2f(u3.z); acc1.w += bf2f(u3.w);
        }
        for (; e < end; ++e) {
            int s0 = e_src[e];
            ushort4 u0 = fb4[s0 * 32 + lane];
            acc0.x += bf2f(u0.x); acc0.y += bf2f(u0.y); acc0.z += bf2f(u0.z); acc0.w += bf2f(u0.w);
        }
        float snd = nd[node];
        float4 acc;
        acc.x = (acc0.x + acc1.x) * snd;
        acc.y = (acc0.y + acc1.y) * snd;
        acc.z = (acc0.z + acc1.z) * snd;
        acc.w = (acc0.w + acc1.w) * snd;
        ((float4*)As)[nl * 32 + lane] = acc;
    }
    __syncthreads();

    const int rr = tid >> 5;  // rows rr*4 .. rr*4+3
    const int cc = tid & 31;  // cols cc*4 .. cc*4+3

    float accC[4][4] = {{0.f}};
    float accR[4][4] = {{0.f}};

    for (int k4 = 0; k4 < 32; ++k4) {
        float4 a4[4], f4[4];
#pragma unroll
        for (int r = 0; r < 4; ++r) {
            a4[r] = ((const float4*)As)[(rr * 4 + r) * 32 + k4];
            f4[r] = ((const float4*)Fs)[(rr * 4 + r) * 32 + k4];
        }
#pragma unroll
        for (int kk = 0; kk < 4; ++kk) {
            int k = k4 * 4 + kk;
            float4 wv = ((const float4*)W)[k * 32 + cc];
            float4 wrv = ((const float4*)Wr)[k * 32 + cc];
#pragma unroll
            for (int r = 0; r < 4; ++r) {
                float a = (kk == 0) ? a4[r].x : (kk == 1) ? a4[r].y : (kk == 2) ? a4[r].z : a4[r].w;
                float f = (kk == 0) ? f4[r].x : (kk == 1) ? f4[r].y : (kk == 2) ? f4[r].z : f4[r].w;
                accC[r][0] += a * wv.x;  accC[r][1] += a * wv.y;
                accC[r][2] += a * wv.z;  accC[r][3] += a * wv.w;
                accR[r][0] += f * wrv.x; accR[r][1] += f * wrv.y;
                accR[r][2] += f * wrv.z; accR[r][3] += f * wrv.w;
            }
        }
    }

    float4 bv = ((const float4*)b)[cc];
    float4 brv = ((const float4*)br)[cc];
    float csum[4] = {0.f, 0.f, 0.f, 0.f};
    float csq[4] = {0.f, 0.f, 0.f, 0.f};
#pragma unroll
    for (int r = 0; r < 4; ++r) {
        int row = block_row + rr * 4 + r;
        float4 o;
        o.x = fmaxf(accC[r][0] + bv.x, 0.f) + fmaxf(accR[r][0] + brv.x, 0.f);
        o.y = fmaxf(accC[r][1] + bv.y, 0.f) + fmaxf(accR[r][1] + brv.y, 0.f);
        o.z = fmaxf(accC[r][2] + bv.z, 0.f) + fmaxf(accR[r][2] + brv.z, 0.f);
        o.w = fmaxf(accC[r][3] + bv.w, 0.f) + fmaxf(accR[r][3] + brv.w, 0.f);
        ((float4*)y)[(size_t)row * 32 + cc] = o;
        csum[0] += o.x; csum[1] += o.y; csum[2] += o.z; csum[3] += o.w;
        csq[0] += o.x * o.x; csq[1] += o.y * o.y; csq[2] += o.z * o.z; csq[3] += o.w * o.w;
    }

    // block-level column reduction: reuse As (sum) and Fs (sumsq)
    __syncthreads();
#pragma unroll
    for (int j = 0; j < 4; ++j) {
        As[rr * 128 + cc * 4 + j] = csum[j];
        Fs[rr * 128 + cc * 4 + j] = csq[j];
    }
    __syncthreads();
    if (tid < 128) {
        float s = 0.f, q = 0.f;
#pragma unroll
        for (int g = 0; g < 8; ++g) {
            s += As[g * 128 + tid];
            q += Fs[g * 128 + tid];
        }
        atomicAdd(&colsum[tid], s);
        atomicAdd(&colsumsq[tid], q);
    }
}

// ---------------- BN stats finalize ----------------
__global__ void stats_kernel(const float* __restrict__ colsum, const float* __restrict__ colsumsq,
                             const float* __restrict__ gamma, const float* __restrict__ beta,
                             float* __restrict__ scale, float* __restrict__ shift) {
    int j = threadIdx.x;
    if (j < DD) {
        float inv_n = 1.0f / (float)NN;
        float mean = colsum[j] * inv_n;
        float var = colsumsq[j] * inv_n - mean * mean;
        float sc = gamma[j] * rsqrtf(var + BN_EPS);
        scale[j] = sc;
        shift[j] = beta[j] - mean * sc;
    }
}

// ---------------- BN apply (in place on d_out) ----------------
__global__ void apply_kernel(float4* __restrict__ y4,
                             const float* __restrict__ scale, const float* __restrict__ shift,
                             int total4) {
    int i = blockIdx.x * blockDim.x + threadIdx.x;
    if (i < total4) {
        int c4 = i & 31;
        float4 v = y4[i];
        float4 sc = ((const float4*)scale)[c4];
        float4 sh = ((const float4*)shift)[c4];
        v.x = v.x * sc.x + sh.x;
        v.y = v.y * sc.y + sh.y;
        v.z = v.z * sc.z + sh.z;
        v.w = v.w * sc.w + sh.w;
        y4[i] = v;
    }
}

extern "C" void kernel_launch(void* const* d_in, const int* in_sizes, int n_in,
                              void* d_out, int out_size, void* d_ws, size_t ws_size,
                              hipStream_t stream) {
    const float* feats = (const float*)d_in[0];
    const int* src = (const int*)d_in[1];
    const int* dst = (const int*)d_in[2];
    const float* W = (const float*)d_in[3];
    const float* b = (const float*)d_in[4];
    const float* Wr = (const float*)d_in[5];
    const float* br = (const float*)d_in[6];
    const float* gamma = (const float*)d_in[7];
    const float* beta = (const float*)d_in[8];
    float* y = (float*)d_out;

    // workspace carve
    char* ws = (char*)d_ws;
    ushort4* fb4 = (ushort4*)ws;                              // NN*32 ushort4 = 25.6 MB
    int* outdeg = (int*)(ws + (size_t)NN * 32 * 8);           // NN
    int* indeg = outdeg + NN;                                 // NN
    float* ns = (float*)(indeg + NN);                         // NN
    float* nd = ns + NN;                                      // NN
    int* row_ofs = (int*)(nd + NN);                           // NN+1
    int* cursor = row_ofs + NN + 1;                           // NN
    int* partial = cursor + NN;                               // NN
    int* blocksum = partial + NN;                             // 98
    int* blockofs = blocksum + 128;                           // 98
    int* e_src = blockofs + 128;                              // EE
    float* colsum = (float*)(e_src + EE);                     // 128
    float* colsumsq = colsum + DD;                            // 128
    float* scale = colsumsq + DD;                             // 128
    float* shift = scale + DD;                                // 128

    hipMemsetAsync(outdeg, 0, 2 * (size_t)NN * sizeof(int), stream);
    hipMemsetAsync(colsum, 0, 2 * (size_t)DD * sizeof(float), stream);

    deg4_kernel<<<(EE / 4 + 255) / 256, 256, 0, stream>>>((const int4*)src, (const int4*)dst,
                                                          outdeg, indeg);
    scan1_kernel<<<98, 1024, 0, stream>>>(indeg, partial, blocksum);
    scan2_kernel<<<1, 128, 0, stream>>>(blocksum, blockofs);
    scan3_kernel<<<(NN + 255) / 256, 256, 0, stream>>>(partial, blockofs, outdeg, indeg,
                                                       row_ofs, cursor, ns, nd);
    cvt_kernel<<<(NN * 32 + 255) / 256, 256, 0, stream>>>((const float4*)feats, ns, fb4);
    fill4_kernel<<<(EE / 4 + 255) / 256, 256, 0, stream>>>((const int4*)src, (const int4*)dst,
                                                           cursor, e_src);
    gg_kernel<<<NN / 32, 256, 0, stream>>>(feats, fb4, nd, row_ofs, e_src,
                                           W, b, Wr, br, y, colsum, colsumsq);
    stats_kernel<<<1, 128, 0, stream>>>(colsum, colsumsq, gamma, beta, scale, shift);
    {
        int total4 = NN * DD / 4;
        apply_kernel<<<(total4 + 255) / 256, 256, 0, stream>>>((float4*)y, scale, shift, total4);
    }
}